// Round 18
// baseline (52.175 us; speedup 1.0000x reference)
//
#include <hip/hip_runtime.h>

typedef _Float16 f16x8 __attribute__((ext_vector_type(8)));
typedef _Float16 f16x4 __attribute__((ext_vector_type(4)));
typedef float    f32x4 __attribute__((ext_vector_type(4)));
typedef unsigned int u32x4 __attribute__((ext_vector_type(4)));

constexpr int NTOK   = 1568;       // T*H*W = 8*14*14
constexpr int NHEADS = 8;
constexpr int NCH    = 512;
constexpr int NC32   = 52;         // 32-token chunks, padded to 1664 tokens (k-loop uses 49)
constexpr float SK   = 0.15014030f; // 0.125*sqrt(log2 e): (q*SK)·(k*SK) = s*log2e/64 -> p = exp2(.)
constexpr size_t IMG_BH = (size_t)NC32 * 4096;   // 212992 B per (bh) per image

// ---- pre-pass: build fragment-major K and V images (every frag = contiguous 1KB, lane*16) ----
__global__ __launch_bounds__(256)
void prep_kernel(const float* __restrict__ x, char* __restrict__ Kimg, char* __restrict__ Vimg)
{
    const int bh = blockIdx.x, c32 = blockIdx.y;
    const int b = bh >> 3, h = bh & 7;
    const int t = threadIdx.x;
    const int f = t >> 6, l = t & 63, l15 = l & 15, grp = l >> 4;

    char* Kg = Kimg + (size_t)bh * IMG_BH + (size_t)(c32 * 4 + f) * 1024 + l * 16;
    char* Vg = Vimg + (size_t)bh * IMG_BH + (size_t)(c32 * 4 + f) * 1024 + l * 16;

    const int n0 = c32 * 32;
    if (n0 >= NTOK) {                       // pure padding chunk
        f16x8 z;
#pragma unroll
        for (int j = 0; j < 8; ++j) z[j] = (_Float16)0.f;
        *(f16x8*)Kg = z; *(f16x8*)Vg = z;
        return;
    }

    __shared__ _Float16 kbuf[32][72];       // [tok][d], scaled
    __shared__ _Float16 vbuf[64][40];       // [d][tok]

    const int tok = t & 31, dhi = t >> 5;   // coalesced: 8 x 128B segments per pass
#pragma unroll
    for (int p = 0; p < 8; ++p) {
        const int d = 8 * p + dhi;
        const float v = x[((size_t)b * NCH + d * NHEADS + h) * NTOK + n0 + tok];
        kbuf[tok][d] = (_Float16)(v * SK);
        vbuf[d][tok] = (_Float16)v;
    }
    __syncthreads();

    // K frag f: cb = f>>1 (16-tok half), ks = f&1
    *(f16x8*)Kg = *(const f16x8*)&kbuf[(f >> 1) * 16 + l15][(f & 1) * 32 + grp * 8];
    // V frag db = f: token quads {4grp..+3} and {16+4grp..+3}
    f16x4 va = *(const f16x4*)&vbuf[f * 16 + l15][4 * grp];
    f16x4 vb = *(const f16x4*)&vbuf[f * 16 + l15][16 + 4 * grp];
    f16x8 vv;
#pragma unroll
    for (int j = 0; j < 4; ++j) { vv[j] = va[j]; vv[4 + j] = vb[j]; }
    *(f16x8*)Vg = vv;
}

// pack 8 exp2(s) values into one P fragment — pure register ops, no union/memory
static __device__ __forceinline__ f16x8 make_bp(f32x4 sA, f32x4 sB)
{
    u32x4 w;
    w[0] = __builtin_bit_cast(unsigned int,
        __builtin_amdgcn_cvt_pkrtz(__builtin_amdgcn_exp2f(sA[0]), __builtin_amdgcn_exp2f(sA[1])));
    w[1] = __builtin_bit_cast(unsigned int,
        __builtin_amdgcn_cvt_pkrtz(__builtin_amdgcn_exp2f(sA[2]), __builtin_amdgcn_exp2f(sA[3])));
    w[2] = __builtin_bit_cast(unsigned int,
        __builtin_amdgcn_cvt_pkrtz(__builtin_amdgcn_exp2f(sB[0]), __builtin_amdgcn_exp2f(sB[1])));
    w[3] = __builtin_bit_cast(unsigned int,
        __builtin_amdgcn_cvt_pkrtz(__builtin_amdgcn_exp2f(sB[2]), __builtin_amdgcn_exp2f(sB[3])));
    return __builtin_bit_cast(f16x8, w);
}

// per-chunk compute for ONE 16-q-row subtile: QK S^T -> exp/pack -> denominator + PV
static __device__ __forceinline__ void chunk_compute(
    const f16x8& k0, const f16x8& k1, const f16x8& k2, const f16x8& k3,
    const f16x8& v0, const f16x8& v1, const f16x8& v2, const f16x8& v3,
    const f16x8 (&aq)[2], const f16x8& ones,
    f32x4 (&oacc)[4], f32x4& lacc)
{
    const f32x4 z4 = {0.f, 0.f, 0.f, 0.f};
    f32x4 sA = __builtin_amdgcn_mfma_f32_16x16x32_f16(k0, aq[0], z4, 0, 0, 0);
    sA = __builtin_amdgcn_mfma_f32_16x16x32_f16(k1, aq[1], sA, 0, 0, 0);
    f32x4 sB = __builtin_amdgcn_mfma_f32_16x16x32_f16(k2, aq[0], z4, 0, 0, 0);
    sB = __builtin_amdgcn_mfma_f32_16x16x32_f16(k3, aq[1], sB, 0, 0, 0);
    const f16x8 bp = make_bp(sA, sB);   // slot j = token 16*(j>>2)+4grp+(j&3)
    lacc    = __builtin_amdgcn_mfma_f32_16x16x32_f16(ones, bp, lacc, 0, 0, 0);
    oacc[0] = __builtin_amdgcn_mfma_f32_16x16x32_f16(v0, bp, oacc[0], 0, 0, 0);
    oacc[1] = __builtin_amdgcn_mfma_f32_16x16x32_f16(v1, bp, oacc[1], 0, 0, 0);
    oacc[2] = __builtin_amdgcn_mfma_f32_16x16x32_f16(v2, bp, oacc[2], 0, 0, 0);
    oacc[3] = __builtin_amdgcn_mfma_f32_16x16x32_f16(v3, bp, oacc[3], 0, 0, 0);
}

// issue one chunk's async staging: 2 x global_load_lds (wave-uniform LDS dst + lane*16)
static __device__ __forceinline__ void stage_chunk(const char* Kb, const char* Vb,
                                                   char* ringbase, int c, int slot,
                                                   int wave, int lane)
{
    const char* gk = Kb + (size_t)c * 4096 + wave * 1024 + lane * 16;
    const char* gv = Vb + (size_t)c * 4096 + wave * 1024 + lane * 16;
    char* lk = ringbase + slot * 8192 + wave * 1024;
    char* lv = ringbase + slot * 8192 + 4096 + wave * 1024;
    __builtin_amdgcn_global_load_lds(gk, lk, 16, 0, 0);
    __builtin_amdgcn_global_load_lds(gv, lv, 16, 0, 0);
}

// ---- main attention: T3/T4 deep-queue pipeline. 6-slot LDS ring, counted vmcnt (never 0),
// raw s_barrier (no vmcnt drain!), 4 waves x 16 q-rows, no combine pass. ----
__global__ __launch_bounds__(256, 3)
void attn_fwd(const char* __restrict__ Kimg, const char* __restrict__ Vimg,
              float* __restrict__ out)
{
    // XCD-aware bijective remap (800 = 8*100): 4 bh per XCD -> both images L2-resident
    const int orig = blockIdx.x;
    const int wgid = (orig & 7) * 100 + (orig >> 3);
    const int qt = wgid % 25, bh = wgid / 25;
    const int b = bh >> 3, head = bh & 7;
    const int t = threadIdx.x, wave = t >> 6, lane = t & 63;
    const int l15 = lane & 15, grp = lane >> 4;

    __shared__ __align__(16) char ring[6][8192];    // 48 KB: [slot][K 4KB | V 4KB]
    char* ringbase = &ring[0][0];

    const char* Kb = Kimg + (size_t)bh * IMG_BH;
    const char* Vb = Vimg + (size_t)bh * IMG_BH;

    // Q fragment for this wave's 16-row subtile (padded image -> always in-bounds)
    const int s16 = qt * 4 + wave;                  // 0..99 < 104 image subtiles
    f16x8 aq[2];
    aq[0] = *(const f16x8*)(Kb + (size_t)(s16 * 2 + 0) * 1024 + lane * 16);
    aq[1] = *(const f16x8*)(Kb + (size_t)(s16 * 2 + 1) * 1024 + lane * 16);
    // drain aq now so the vmcnt queue below contains ONLY staging DMAs (exact counting)
    asm volatile("s_waitcnt vmcnt(0)" ::: "memory");
    __builtin_amdgcn_sched_barrier(0);

    f16x8 ones;
#pragma unroll
    for (int j = 0; j < 8; ++j) ones[j] = (_Float16)1.f;

    f32x4 oacc[4];
    f32x4 lacc = {0.f, 0.f, 0.f, 0.f};
#pragma unroll
    for (int db = 0; db < 4; ++db) oacc[db] = f32x4{0.f, 0.f, 0.f, 0.f};

    // prologue: queue chunks 0..5 (12 DMAs/wave outstanding)
#pragma unroll
    for (int c = 0; c < 6; ++c)
        stage_chunk(Kb, Vb, ringbase, c, c, wave, lane);

    int slot = 0;
    for (int c = 0; c < 49; ++c) {      // 49 x 32 = 1568 tokens exactly
        // chunk c's 2 DMAs are the oldest 2 of 12 outstanding -> counted wait, never 0
        asm volatile("s_waitcnt vmcnt(10)" ::: "memory");
        __builtin_amdgcn_sched_barrier(0);
        __builtin_amdgcn_s_barrier();               // raw: no compiler vmcnt(0) drain
        __builtin_amdgcn_sched_barrier(0);          // pin ds_reads below the barrier

        const char* basep = ringbase + slot * 8192;
        f16x8 k0 = *(const f16x8*)(basep + lane * 16);
        f16x8 k1 = *(const f16x8*)(basep + 1024 + lane * 16);
        f16x8 k2 = *(const f16x8*)(basep + 2048 + lane * 16);
        f16x8 k3 = *(const f16x8*)(basep + 3072 + lane * 16);
        f16x8 v0 = *(const f16x8*)(basep + 4096 + lane * 16);
        f16x8 v1 = *(const f16x8*)(basep + 5120 + lane * 16);
        f16x8 v2 = *(const f16x8*)(basep + 6144 + lane * 16);
        f16x8 v3 = *(const f16x8*)(basep + 7168 + lane * 16);
        chunk_compute(k0, k1, k2, k3, v0, v1, v2, v3, aq, ones, oacc, lacc);

        asm volatile("s_waitcnt lgkmcnt(0)" ::: "memory");   // all slot reads complete
        __builtin_amdgcn_sched_barrier(0);          // pin reads above barrier-2
        __builtin_amdgcn_s_barrier();               // all waves done reading this slot
        __builtin_amdgcn_sched_barrier(0);

        // refill the freed slot with chunk c+6 (clamped into padded image -> uniform counting)
        const int sc = (c + 6 < 52) ? (c + 6) : 51;
        stage_chunk(Kb, Vb, ringbase, sc, slot, wave, lane);

        slot = (slot == 5) ? 0 : slot + 1;
    }

    // ---- store: each wave owns its 16 q-rows outright (full k-range -> no combine) ----
    if (s16 < 98) {                     // 98*16 = 1568: wave-uniform validity
        const int qrow = s16 * 16 + l15;
        const float inv = 1.0f / lacc[0];            // denominator for column q = l15
#pragma unroll
        for (int db = 0; db < 4; ++db)
#pragma unroll
            for (int q = 0; q < 4; ++q) {
                const int d = db * 16 + 4 * grp + q; // O^T: row=d, col=q
                out[((size_t)b * NCH + (size_t)d * NHEADS + head) * NTOK + qrow] = oacc[db][q] * inv;
            }
    }
}

extern "C" void kernel_launch(void* const* d_in, const int* in_sizes, int n_in,
                              void* d_out, int out_size, void* d_ws, size_t ws_size,
                              hipStream_t stream)
{
    const float* x = (const float*)d_in[0];
    float* out     = (float*)d_out;

    char* Kimg = (char*)d_ws;                       // 32 * 208KB = 6.8 MB
    char* Vimg = (char*)d_ws + 32 * IMG_BH;         // + 6.8 MB

    dim3 pgrid(32, NC32);                           // 32 bh x 52 chunks
    prep_kernel<<<pgrid, 256, 0, stream>>>(x, Kimg, Vimg);

    attn_fwd<<<800, 256, 0, stream>>>(Kimg, Vimg, out);   // 25 q-tiles x 32 bh, XCD-remapped
}

// Round 19
// 43.315 us; speedup vs baseline: 1.2045x; 1.2045x over previous
//
#include <hip/hip_runtime.h>

typedef _Float16 f16x8 __attribute__((ext_vector_type(8)));
typedef _Float16 f16x4 __attribute__((ext_vector_type(4)));
typedef float    f32x4 __attribute__((ext_vector_type(4)));
typedef unsigned int u32x4 __attribute__((ext_vector_type(4)));

constexpr int NTOK   = 1568;       // T*H*W = 8*14*14
constexpr int NHEADS = 8;
constexpr int NCH    = 512;
constexpr int NC32   = 52;         // 32-token chunks, padded to 1664 tokens
constexpr float SK   = 0.15014030f; // 0.125*sqrt(log2 e): (q*SK)·(k*SK) = s*log2e/64 -> p = exp2(.)
constexpr size_t IMG_BH = (size_t)NC32 * 4096;   // 212992 B per (bh) per image

// ---- pre-pass: build fragment-major K and V images (every frag = contiguous 1KB, lane*16) ----
__global__ __launch_bounds__(256)
void prep_kernel(const float* __restrict__ x, char* __restrict__ Kimg, char* __restrict__ Vimg)
{
    const int bh = blockIdx.x, c32 = blockIdx.y;
    const int b = bh >> 3, h = bh & 7;
    const int t = threadIdx.x;
    const int f = t >> 6, l = t & 63, l15 = l & 15, grp = l >> 4;

    char* Kg = Kimg + (size_t)bh * IMG_BH + (size_t)(c32 * 4 + f) * 1024 + l * 16;
    char* Vg = Vimg + (size_t)bh * IMG_BH + (size_t)(c32 * 4 + f) * 1024 + l * 16;

    const int n0 = c32 * 32;
    if (n0 >= NTOK) {                       // pure padding chunk: zeros (K=0 -> p=1, V=0)
        f16x8 z;
#pragma unroll
        for (int j = 0; j < 8; ++j) z[j] = (_Float16)0.f;
        *(f16x8*)Kg = z; *(f16x8*)Vg = z;
        return;
    }

    __shared__ _Float16 kbuf[32][72];       // [tok][d], scaled
    __shared__ _Float16 vbuf[64][40];       // [d][tok]

    const int tok = t & 31, dhi = t >> 5;   // coalesced: 8 x 128B segments per pass
#pragma unroll
    for (int p = 0; p < 8; ++p) {
        const int d = 8 * p + dhi;
        const float v = x[((size_t)b * NCH + d * NHEADS + h) * NTOK + n0 + tok];
        kbuf[tok][d] = (_Float16)(v * SK);
        vbuf[d][tok] = (_Float16)v;
    }
    __syncthreads();

    // K frag f: cb = f>>1 (16-tok half), ks = f&1
    *(f16x8*)Kg = *(const f16x8*)&kbuf[(f >> 1) * 16 + l15][(f & 1) * 32 + grp * 8];
    // V frag db = f: token quads {4grp..+3} and {16+4grp..+3}
    f16x4 va = *(const f16x4*)&vbuf[f * 16 + l15][4 * grp];
    f16x4 vb = *(const f16x4*)&vbuf[f * 16 + l15][16 + 4 * grp];
    f16x8 vv;
#pragma unroll
    for (int j = 0; j < 4; ++j) { vv[j] = va[j]; vv[4 + j] = vb[j]; }
    *(f16x8*)Vg = vv;
}

// pack 8 exp2(s) values into one P fragment — pure register ops, no union/memory
static __device__ __forceinline__ f16x8 make_bp(f32x4 sA, f32x4 sB)
{
    u32x4 w;
    w[0] = __builtin_bit_cast(unsigned int,
        __builtin_amdgcn_cvt_pkrtz(__builtin_amdgcn_exp2f(sA[0]), __builtin_amdgcn_exp2f(sA[1])));
    w[1] = __builtin_bit_cast(unsigned int,
        __builtin_amdgcn_cvt_pkrtz(__builtin_amdgcn_exp2f(sA[2]), __builtin_amdgcn_exp2f(sA[3])));
    w[2] = __builtin_bit_cast(unsigned int,
        __builtin_amdgcn_cvt_pkrtz(__builtin_amdgcn_exp2f(sB[0]), __builtin_amdgcn_exp2f(sB[1])));
    w[3] = __builtin_bit_cast(unsigned int,
        __builtin_amdgcn_cvt_pkrtz(__builtin_amdgcn_exp2f(sB[2]), __builtin_amdgcn_exp2f(sB[3])));
    return __builtin_bit_cast(f16x8, w);
}

// combine helpers: statically-indexed register arrays by reference (inlined -> stays in VGPRs)
static __device__ __forceinline__ void dump_part(float (*row)[69], int lane,
                                                 const f32x4 (&oacc)[4][4], const f32x4 (&lacc)[4])
{
#pragma unroll
    for (int s = 0; s < 4; ++s) {
#pragma unroll
        for (int db = 0; db < 4; ++db)
#pragma unroll
            for (int q = 0; q < 4; ++q) row[lane][s * 16 + db * 4 + q] = oacc[s][db][q];
        row[lane][64 + s] = lacc[s][0];
    }
}
static __device__ __forceinline__ void add_part(const float (*row)[69], int lane,
                                                f32x4 (&oacc)[4][4], f32x4 (&lacc)[4])
{
#pragma unroll
    for (int s = 0; s < 4; ++s) {
#pragma unroll
        for (int db = 0; db < 4; ++db)
#pragma unroll
            for (int q = 0; q < 4; ++q) oacc[s][db][q] += row[lane][s * 16 + db * 4 + q];
        lacc[s][0] += row[lane][64 + s];
    }
}

// ---- main attention: r9 structure with 64-token BIG chunks (half the dependent rounds).
// 4 waves x 4 subs (64 q-rows), k-split 7/6/6/6 over 25 big chunks. Plain loop body:
// the compiler schedules/hoists loads (r12/r18 lesson: do NOT pin the schedule). ----
__global__ __launch_bounds__(256, 2)
void attn_fwd(const char* __restrict__ Kimg, const char* __restrict__ Vimg,
              float* __restrict__ out)
{
    // XCD-aware bijective remap (800 = 8*100): 4 bh per XCD -> both images L2-resident
    const int orig = blockIdx.x;
    const int wgid = (orig & 7) * 100 + (orig >> 3);
    const int qt = wgid % 25, bh = wgid / 25;
    const int b = bh >> 3, head = bh & 7;
    const int t = threadIdx.x, kw = t >> 6, lane = t & 63;
    const int l15 = lane & 15, grp = lane >> 4;

    const char* Kb = Kimg + (size_t)bh * IMG_BH;
    const char* Vb = Vimg + (size_t)bh * IMG_BH;

    // Q fragments (B operand, col = l15 = q-row), from the padded K image (scale baked in)
    f16x8 aq[4][2];
#pragma unroll
    for (int sub = 0; sub < 4; ++sub)
#pragma unroll
        for (int ks = 0; ks < 2; ++ks)
            aq[sub][ks] = *(const f16x8*)(Kb + (size_t)((qt * 4 + sub) * 2 + ks) * 1024 + lane * 16);

    f16x8 ones;
#pragma unroll
    for (int j = 0; j < 8; ++j) ones[j] = (_Float16)1.f;

    f32x4 oacc[4][4];
    f32x4 lacc[4];
#pragma unroll
    for (int s = 0; s < 4; ++s) {
        lacc[s] = f32x4{0.f, 0.f, 0.f, 0.f};
#pragma unroll
        for (int db = 0; db < 4; ++db) oacc[s][db] = f32x4{0.f, 0.f, 0.f, 0.f};
    }

    // 25 big chunks (64 tok; chunk 24 half-padding) split 7/6/6/6 across the 4 kw waves
    const int start = (kw == 0) ? 0 : 7 + (kw - 1) * 6;
    const int nc    = (kw == 0) ? 7 : 6;
    const f32x4 z4 = {0.f, 0.f, 0.f, 0.f};

    for (int i = 0; i < nc; ++i) {
        const char* kbase = Kb + (size_t)(start + i) * 8192 + lane * 16;
        const char* vbase = Vb + (size_t)(start + i) * 8192 + lane * 16;

        // K frags: f = cb*2+ks for tokens (f>>1)*16..+15; V frags: c32loc*4+db
        f16x8 kf0 = *(const f16x8*)(kbase);
        f16x8 kf1 = *(const f16x8*)(kbase + 1024);
        f16x8 kf2 = *(const f16x8*)(kbase + 2048);
        f16x8 kf3 = *(const f16x8*)(kbase + 3072);
        f16x8 kf4 = *(const f16x8*)(kbase + 4096);
        f16x8 kf5 = *(const f16x8*)(kbase + 5120);
        f16x8 kf6 = *(const f16x8*)(kbase + 6144);
        f16x8 kf7 = *(const f16x8*)(kbase + 7168);
        f16x8 vf00 = *(const f16x8*)(vbase);
        f16x8 vf01 = *(const f16x8*)(vbase + 1024);
        f16x8 vf02 = *(const f16x8*)(vbase + 2048);
        f16x8 vf03 = *(const f16x8*)(vbase + 3072);
        f16x8 vf10 = *(const f16x8*)(vbase + 4096);
        f16x8 vf11 = *(const f16x8*)(vbase + 5120);
        f16x8 vf12 = *(const f16x8*)(vbase + 6144);
        f16x8 vf13 = *(const f16x8*)(vbase + 7168);

#pragma unroll
        for (int sub = 0; sub < 4; ++sub) {
            f32x4 sA = __builtin_amdgcn_mfma_f32_16x16x32_f16(kf0, aq[sub][0], z4, 0, 0, 0);
            sA = __builtin_amdgcn_mfma_f32_16x16x32_f16(kf1, aq[sub][1], sA, 0, 0, 0);
            f32x4 sB = __builtin_amdgcn_mfma_f32_16x16x32_f16(kf2, aq[sub][0], z4, 0, 0, 0);
            sB = __builtin_amdgcn_mfma_f32_16x16x32_f16(kf3, aq[sub][1], sB, 0, 0, 0);
            f32x4 sC = __builtin_amdgcn_mfma_f32_16x16x32_f16(kf4, aq[sub][0], z4, 0, 0, 0);
            sC = __builtin_amdgcn_mfma_f32_16x16x32_f16(kf5, aq[sub][1], sC, 0, 0, 0);
            f32x4 sD = __builtin_amdgcn_mfma_f32_16x16x32_f16(kf6, aq[sub][0], z4, 0, 0, 0);
            sD = __builtin_amdgcn_mfma_f32_16x16x32_f16(kf7, aq[sub][1], sD, 0, 0, 0);
            const f16x8 bp0 = make_bp(sA, sB);   // tokens 0..31 of the big chunk
            const f16x8 bp1 = make_bp(sC, sD);   // tokens 32..63
            lacc[sub]    = __builtin_amdgcn_mfma_f32_16x16x32_f16(ones, bp0, lacc[sub], 0, 0, 0);
            lacc[sub]    = __builtin_amdgcn_mfma_f32_16x16x32_f16(ones, bp1, lacc[sub], 0, 0, 0);
            oacc[sub][0] = __builtin_amdgcn_mfma_f32_16x16x32_f16(vf00, bp0, oacc[sub][0], 0, 0, 0);
            oacc[sub][1] = __builtin_amdgcn_mfma_f32_16x16x32_f16(vf01, bp0, oacc[sub][1], 0, 0, 0);
            oacc[sub][2] = __builtin_amdgcn_mfma_f32_16x16x32_f16(vf02, bp0, oacc[sub][2], 0, 0, 0);
            oacc[sub][3] = __builtin_amdgcn_mfma_f32_16x16x32_f16(vf03, bp0, oacc[sub][3], 0, 0, 0);
            oacc[sub][0] = __builtin_amdgcn_mfma_f32_16x16x32_f16(vf10, bp1, oacc[sub][0], 0, 0, 0);
            oacc[sub][1] = __builtin_amdgcn_mfma_f32_16x16x32_f16(vf11, bp1, oacc[sub][1], 0, 0, 0);
            oacc[sub][2] = __builtin_amdgcn_mfma_f32_16x16x32_f16(vf12, bp1, oacc[sub][2], 0, 0, 0);
            oacc[sub][3] = __builtin_amdgcn_mfma_f32_16x16x32_f16(vf13, bp1, oacc[sub][3], 0, 0, 0);
        }
    }

    // ---- combine the 4 kw waves (sequential rounds, one small LDS buffer) ----
    __shared__ float comb[64][69];          // stride 69: gcd(69,32)=1, conflict-free
    for (int r = 1; r < 4; ++r) {
        if (kw == r) dump_part(comb, lane, oacc, lacc);
        __syncthreads();
        if (kw == 0) add_part(comb, lane, oacc, lacc);
        __syncthreads();
    }

    if (kw == 0) {
        // lacc[s][0] = denominator for column q = l15, PLUS exactly 32.0 from chunk 24's
        // zero-padded tokens (K=0 -> p=1.0 each, V=0 -> oacc untouched) -> subtract.
#pragma unroll
        for (int sub = 0; sub < 4; ++sub) {
            const int qrow = qt * 64 + sub * 16 + l15;
            if (qrow < NTOK) {
                const float inv = 1.0f / (lacc[sub][0] - 32.0f);
#pragma unroll
                for (int db = 0; db < 4; ++db)
#pragma unroll
                    for (int q = 0; q < 4; ++q) {
                        const int d = db * 16 + 4 * grp + q;   // O^T: row=d, col=q
                        out[((size_t)b * NCH + (size_t)d * NHEADS + head) * NTOK + qrow] = oacc[sub][db][q] * inv;
                    }
            }
        }
    }
}

extern "C" void kernel_launch(void* const* d_in, const int* in_sizes, int n_in,
                              void* d_out, int out_size, void* d_ws, size_t ws_size,
                              hipStream_t stream)
{
    const float* x = (const float*)d_in[0];
    float* out     = (float*)d_out;

    char* Kimg = (char*)d_ws;                       // 32 * 208KB = 6.8 MB
    char* Vimg = (char*)d_ws + 32 * IMG_BH;         // + 6.8 MB

    dim3 pgrid(32, NC32);                           // 32 bh x 52 chunks
    prep_kernel<<<pgrid, 256, 0, stream>>>(x, Kimg, Vimg);

    attn_fwd<<<800, 256, 0, stream>>>(Kimg, Vimg, out);   // 25 q-tiles x 32 bh, XCD-remapped
}

// Round 20
// 43.210 us; speedup vs baseline: 1.2075x; 1.0024x over previous
//
#include <hip/hip_runtime.h>

typedef _Float16 f16x8 __attribute__((ext_vector_type(8)));
typedef _Float16 f16x4 __attribute__((ext_vector_type(4)));
typedef float    f32x4 __attribute__((ext_vector_type(4)));
typedef unsigned int u32x4 __attribute__((ext_vector_type(4)));

constexpr int NTOK   = 1568;       // T*H*W = 8*14*14
constexpr int NHEADS = 8;
constexpr int NCH    = 512;
constexpr int NC32   = 52;         // 32-token chunks, padded to 1664 tokens
constexpr float SK   = 0.15014030f; // 0.125*sqrt(log2 e): (q*SK)·(k*SK) = s*log2e/64 -> p = exp2(.)
constexpr size_t IMG_BH = (size_t)NC32 * 4096;   // 212992 B per (bh) per image

// ---- pre-pass: build fragment-major K and V images (every frag = contiguous 1KB, lane*16) ----
// K frag (c16 = tok/16, ks): slot(l15,grp,j) = x[tok=c16*16+l15][d=ks*32+8grp+j] * SK
// V frag (c32 = tok/32, db): slot(l15,grp,j) = x[tok=c32*32+16*(j>>2)+4grp+(j&3)][d=db*16+l15]
__global__ __launch_bounds__(256)
void prep_kernel(const float* __restrict__ x, char* __restrict__ Kimg, char* __restrict__ Vimg)
{
    const int bh = blockIdx.x, c32 = blockIdx.y;
    const int b = bh >> 3, h = bh & 7;
    const int t = threadIdx.x;
    const int f = t >> 6, l = t & 63, l15 = l & 15, grp = l >> 4;

    char* Kg = Kimg + (size_t)bh * IMG_BH + (size_t)(c32 * 4 + f) * 1024 + l * 16;
    char* Vg = Vimg + (size_t)bh * IMG_BH + (size_t)(c32 * 4 + f) * 1024 + l * 16;

    const int n0 = c32 * 32;
    if (n0 >= NTOK) {                       // pure padding chunk
        f16x8 z;
#pragma unroll
        for (int j = 0; j < 8; ++j) z[j] = (_Float16)0.f;
        *(f16x8*)Kg = z; *(f16x8*)Vg = z;
        return;
    }

    __shared__ _Float16 kbuf[32][72];       // [tok][d], scaled
    __shared__ _Float16 vbuf[64][40];       // [d][tok]

    const int tok = t & 31, dhi = t >> 5;   // coalesced: 8 x 128B segments per pass
#pragma unroll
    for (int p = 0; p < 8; ++p) {
        const int d = 8 * p + dhi;
        const float v = x[((size_t)b * NCH + d * NHEADS + h) * NTOK + n0 + tok];
        kbuf[tok][d] = (_Float16)(v * SK);
        vbuf[d][tok] = (_Float16)v;
    }
    __syncthreads();

    // K frag f: cb = f>>1 (16-tok half), ks = f&1
    *(f16x8*)Kg = *(const f16x8*)&kbuf[(f >> 1) * 16 + l15][(f & 1) * 32 + grp * 8];
    // V frag db = f: token quads {4grp..+3} and {16+4grp..+3}
    f16x4 va = *(const f16x4*)&vbuf[f * 16 + l15][4 * grp];
    f16x4 vb = *(const f16x4*)&vbuf[f * 16 + l15][16 + 4 * grp];
    f16x8 vv;
#pragma unroll
    for (int j = 0; j < 4; ++j) { vv[j] = va[j]; vv[4 + j] = vb[j]; }
    *(f16x8*)Vg = vv;
}

// pack 8 exp2(s) values into one P fragment — pure register ops, no union/memory
static __device__ __forceinline__ f16x8 make_bp(f32x4 sA, f32x4 sB)
{
    u32x4 w;
    w[0] = __builtin_bit_cast(unsigned int,
        __builtin_amdgcn_cvt_pkrtz(__builtin_amdgcn_exp2f(sA[0]), __builtin_amdgcn_exp2f(sA[1])));
    w[1] = __builtin_bit_cast(unsigned int,
        __builtin_amdgcn_cvt_pkrtz(__builtin_amdgcn_exp2f(sA[2]), __builtin_amdgcn_exp2f(sA[3])));
    w[2] = __builtin_bit_cast(unsigned int,
        __builtin_amdgcn_cvt_pkrtz(__builtin_amdgcn_exp2f(sB[0]), __builtin_amdgcn_exp2f(sB[1])));
    w[3] = __builtin_bit_cast(unsigned int,
        __builtin_amdgcn_cvt_pkrtz(__builtin_amdgcn_exp2f(sB[2]), __builtin_amdgcn_exp2f(sB[3])));
    return __builtin_bit_cast(f16x8, w);
}

// combine helpers: statically-indexed register arrays by reference (inlined -> stays in VGPRs)
static __device__ __forceinline__ void dump_part(float (*row)[35], int lane,
                                                 const f32x4 (&oacc)[2][4], const f32x4 (&lacc)[2])
{
#pragma unroll
    for (int s = 0; s < 2; ++s) {
#pragma unroll
        for (int db = 0; db < 4; ++db)
#pragma unroll
            for (int q = 0; q < 4; ++q) row[lane][s * 16 + db * 4 + q] = oacc[s][db][q];
        row[lane][32 + s] = lacc[s][0];
    }
}
static __device__ __forceinline__ void add_part(const float (*row)[35], int lane,
                                                f32x4 (&oacc)[2][4], f32x4 (&lacc)[2])
{
#pragma unroll
    for (int s = 0; s < 2; ++s) {
#pragma unroll
        for (int db = 0; db < 4; ++db)
#pragma unroll
            for (int q = 0; q < 4; ++q) oacc[s][db][q] += row[lane][s * 16 + db * 4 + q];
        lacc[s][0] += row[lane][32 + s];
    }
}

// ---- main attention: QBLK=32 (2 subs/wave), 4 waves k-split, no LDS/barriers in hot loop.
// T5: setprio(1) around the MFMA/exp cluster — waves free-run at different chunk phases
// (m191-positive regime), so compute-phase waves preempt load-issuing waves on the SIMD. ----
__global__ __launch_bounds__(256, 4)
void attn_fwd(const char* __restrict__ Kimg, const char* __restrict__ Vimg,
              float* __restrict__ out)
{
    // XCD-aware bijective remap (1568 = 8*196): 4 bh per XCD -> both images L2-resident
    const int orig = blockIdx.x;
    const int wgid = (orig & 7) * 196 + (orig >> 3);
    const int qt = wgid % 49, bh = wgid / 49;       // qt: 32-row q-tile, 49*32 = 1568 exactly
    const int b = bh >> 3, head = bh & 7;
    const int t = threadIdx.x, kw = t >> 6, lane = t & 63;
    const int l15 = lane & 15, grp = lane >> 4;

    const char* Kb = Kimg + (size_t)bh * IMG_BH;
    const char* Vb = Vimg + (size_t)bh * IMG_BH;

    // Q fragments: B operand (col = l15 = q-row), from the padded K image (scale baked in)
    f16x8 aq[2][2];
#pragma unroll
    for (int sub = 0; sub < 2; ++sub)
#pragma unroll
        for (int ks = 0; ks < 2; ++ks)
            aq[sub][ks] = *(const f16x8*)(Kb + (size_t)((qt * 2 + sub) * 2 + ks) * 1024 + lane * 16);

    f16x8 ones;
#pragma unroll
    for (int j = 0; j < 8; ++j) ones[j] = (_Float16)1.f;

    f32x4 oacc[2][4];
    f32x4 lacc[2];
#pragma unroll
    for (int s = 0; s < 2; ++s) {
        lacc[s] = f32x4{0.f, 0.f, 0.f, 0.f};
#pragma unroll
        for (int db = 0; db < 4; ++db) oacc[s][db] = f32x4{0.f, 0.f, 0.f, 0.f};
    }

    // 49 valid chunks split 13/12/12/12 across the 4 kw waves
    const int start = (kw == 0) ? 0 : 13 + (kw - 1) * 12;
    const int nc    = (kw == 0) ? 13 : 12;
    const f32x4 z4 = {0.f, 0.f, 0.f, 0.f};

    for (int i = 0; i < nc; ++i) {
        const int c32 = start + i;
        const char* kbase = Kb + (size_t)c32 * 4096 + lane * 16;
        const char* vbase = Vb + (size_t)c32 * 4096 + lane * 16;

        f16x8 ka0 = *(const f16x8*)(kbase);
        f16x8 ka1 = *(const f16x8*)(kbase + 1024);
        f16x8 kb0 = *(const f16x8*)(kbase + 2048);
        f16x8 kb1 = *(const f16x8*)(kbase + 3072);
        f16x8 vf0 = *(const f16x8*)(vbase);
        f16x8 vf1 = *(const f16x8*)(vbase + 1024);
        f16x8 vf2 = *(const f16x8*)(vbase + 2048);
        f16x8 vf3 = *(const f16x8*)(vbase + 3072);

        // per q-subgroup: S^T both 16-token halves -> pack P -> denominator + PV MFMAs
        __builtin_amdgcn_s_setprio(1);
#pragma unroll
        for (int sub = 0; sub < 2; ++sub) {
            f32x4 sA = __builtin_amdgcn_mfma_f32_16x16x32_f16(ka0, aq[sub][0], z4, 0, 0, 0);
            sA = __builtin_amdgcn_mfma_f32_16x16x32_f16(ka1, aq[sub][1], sA, 0, 0, 0);
            f32x4 sB = __builtin_amdgcn_mfma_f32_16x16x32_f16(kb0, aq[sub][0], z4, 0, 0, 0);
            sB = __builtin_amdgcn_mfma_f32_16x16x32_f16(kb1, aq[sub][1], sB, 0, 0, 0);
            const f16x8 bp = make_bp(sA, sB);   // slot j = token 16*(j>>2)+4grp+(j&3)
            lacc[sub]    = __builtin_amdgcn_mfma_f32_16x16x32_f16(ones, bp, lacc[sub], 0, 0, 0);
            oacc[sub][0] = __builtin_amdgcn_mfma_f32_16x16x32_f16(vf0, bp, oacc[sub][0], 0, 0, 0);
            oacc[sub][1] = __builtin_amdgcn_mfma_f32_16x16x32_f16(vf1, bp, oacc[sub][1], 0, 0, 0);
            oacc[sub][2] = __builtin_amdgcn_mfma_f32_16x16x32_f16(vf2, bp, oacc[sub][2], 0, 0, 0);
            oacc[sub][3] = __builtin_amdgcn_mfma_f32_16x16x32_f16(vf3, bp, oacc[sub][3], 0, 0, 0);
        }
        __builtin_amdgcn_s_setprio(0);
    }

    // ---- combine the 4 kw waves (sequential rounds, one small LDS buffer) ----
    __shared__ float comb[64][35];          // stride 35 (odd): worst 2-way banks = free
    for (int r = 1; r < 4; ++r) {
        if (kw == r) dump_part(comb, lane, oacc, lacc);
        __syncthreads();
        if (kw == 0) add_part(comb, lane, oacc, lacc);
        __syncthreads();
    }

    if (kw == 0) {
        // lacc[s][0] is the full denominator for column q = l15 (MFMA reduced all k in-instruction)
#pragma unroll
        for (int sub = 0; sub < 2; ++sub) {
            const int qrow = qt * 32 + sub * 16 + l15;      // always < 1568
            const float inv = 1.0f / lacc[sub][0];
#pragma unroll
            for (int db = 0; db < 4; ++db)
#pragma unroll
                for (int q = 0; q < 4; ++q) {
                    const int d = db * 16 + 4 * grp + q;    // O^T: row=d, col=q
                    out[((size_t)b * NCH + (size_t)d * NHEADS + head) * NTOK + qrow] = oacc[sub][db][q] * inv;
                }
        }
    }
}

extern "C" void kernel_launch(void* const* d_in, const int* in_sizes, int n_in,
                              void* d_out, int out_size, void* d_ws, size_t ws_size,
                              hipStream_t stream)
{
    const float* x = (const float*)d_in[0];
    float* out     = (float*)d_out;

    char* Kimg = (char*)d_ws;                       // 32 * 208KB = 6.8 MB
    char* Vimg = (char*)d_ws + 32 * IMG_BH;         // + 6.8 MB

    dim3 pgrid(32, NC32);                           // 32 bh x 52 chunks
    prep_kernel<<<pgrid, 256, 0, stream>>>(x, Kimg, Vimg);

    attn_fwd<<<1568, 256, 0, stream>>>(Kimg, Vimg, out);   // 49 q-tiles x 32 bh, XCD-remapped
}